// Round 13
// baseline (287.690 us; speedup 1.0000x reference)
//
#include <hip/hip_runtime.h>
#include <hip/hip_fp16.h>
#include <stdint.h>
#include <math.h>

#define BS    2
#define RAYS  514
#define NS    64
#define LSEQ  512
#define NF    257
#define HIDN  64
#define SPLIT 4
#define JC    16      // hidden columns per k2 block

#define TWO_PI_F 6.28318530717958647692f

__device__ __forceinline__ uint32_t rotl32(uint32_t x, int d){ return (x<<d)|(x>>(32-d)); }

__device__ __forceinline__ void tf_rounds4(uint32_t& x0, uint32_t& x1, int a, int b, int c, int d){
  x0+=x1; x1=rotl32(x1,a); x1^=x0;
  x0+=x1; x1=rotl32(x1,b); x1^=x0;
  x0+=x1; x1=rotl32(x1,c); x1^=x0;
  x0+=x1; x1=rotl32(x1,d); x1^=x0;
}

// Threefry-2x32, 20 rounds, matching jax._src.prng.threefry2x32
__device__ void threefry2x32(uint32_t k0, uint32_t k1, uint32_t x0, uint32_t x1,
                             uint32_t& o0, uint32_t& o1)
{
  const uint32_t ks2 = k0 ^ k1 ^ 0x1BD11BDAu;
  x0 += k0; x1 += k1;
  tf_rounds4(x0,x1,13,15,26,6);   x0+=k1;  x1+=ks2+1u;
  tf_rounds4(x0,x1,17,29,16,24);  x0+=ks2; x1+=k0+2u;
  tf_rounds4(x0,x1,13,15,26,6);   x0+=k0;  x1+=k1+3u;
  tf_rounds4(x0,x1,17,29,16,24);  x0+=k1;  x1+=ks2+4u;
  tf_rounds4(x0,x1,13,15,26,6);   x0+=ks2; x1+=k0+5u;
  o0 = x0; o1 = x1;
}

// Reproduces _ray_directions() for ray r (verified round 0).
__device__ void ray_dir(int r, float d[3])
{
  if (r >= 512) { d[0]=0.f; d[1]=0.f; d[2] = (r==512) ? 1.0f : -1.0f; return; }
  int i = r >> 4, j = r & 15;
  uint32_t o0, o1;
  threefry2x32(0u, 42u, 0u, (uint32_t)i, o0, o1);
  uint32_t bits = o0 ^ o1;
  float u = __uint_as_float((bits >> 9) | 0x3F800000u) - 1.0f;   // uniform [0,1)
  const float step = TWO_PI_F / 32.0f;
  float a = (float)i * step + step * u;
  float e = acosf(2.0f * ((float)(j+1) * (1.0f/17.0f)) - 1.0f);
  float se = sinf(e);
  d[0] = cosf(a) * se;
  d[1] = sinf(a) * se;
  d[2] = cosf(e);
}

__device__ __forceinline__ float dval(int s){ return ((float)s*(1.0f/63.0f))*7.9f + 0.1f; }

__device__ __forceinline__ uint32_t pk2(float a, float b){
  return (uint32_t)__half_as_ushort(__float2half(a)) |
         ((uint32_t)__half_as_ushort(__float2half(b)) << 16);
}

// K1: R10 proven form (4 waves/block, one (b,r) per wave; lane = s).
// Zeroes g, out, and the per-bsid arrival counters each replay.
__global__ __launch_bounds__(256)
void k1_rays(const float* __restrict__ rays_o, const float* __restrict__ position_tx,
             const float* __restrict__ W1, const float* __restrict__ b1,
             const float* __restrict__ w_attn,
             __half* __restrict__ wh, float* __restrict__ w_arr, int* __restrict__ delay_arr,
             float* __restrict__ g, float* __restrict__ out, int* __restrict__ cnt)
{
  const int tid = threadIdx.x;
  const int wid = tid >> 6, lane = tid & 63;       // lane = s index
  const int br = blockIdx.x*4 + wid;               // 257*4 = 1028 = BS*RAYS
  const int b = br / RAYS, r = br % RAYS;

  { // zero the atomic accumulators (65792 threads cover g:65536 and out:1028)
    int gi = blockIdx.x*256 + tid;
    if (gi < BS*NS*LSEQ) g[gi] = 0.f;
    if (gi < BS*NF*2) out[gi] = 0.f;
    if (blockIdx.x == 0 && tid < BS*NS) cnt[tid] = 0;
  }

  float dir[3]; ray_dir(r, dir);
  const float mn[3] = {-5.f,-5.f,-3.f}, mx[3] = {5.f,5.f,3.f};
  float ro[3], ntx[3];
  #pragma unroll
  for (int c=0;c<3;c++){
    ro[c] = rays_o[b*3+c];
    float t = position_tx[b*3+c];
    ntx[c] = 2.0f*(t - mn[c])/(mx[c]-mn[c]) - 1.0f;
  }

  const float dv = dval(lane);
  float feat[9], dd2 = 0.f;
  #pragma unroll
  for (int c=0;c<3;c++){
    float pt = ro[c] + dir[c]*dv;
    float npt = 2.0f*(pt - mn[c])/(mx[c]-mn[c]) - 1.0f;
    float ddc = ((ntx[c]-npt) + 1.0f)/2.0f*(mx[c]-mn[c]) + mn[c];
    dd2 += ddc*ddc;
    feat[c]   = npt;
    feat[3+c] = -dir[c];
    feat[6+c] = ntx[c];
  }

  float h[HIDN];
  float av = 0.f;
  #pragma unroll
  for (int j=0; j<HIDN; j++){
    float hj = b1[j];
    #pragma unroll
    for (int f=0; f<9; f++) hj = fmaf(feat[f], W1[f*HIDN + j], hj);
    hj = fmaxf(hj, 0.0f);
    h[j] = hj;
    av = fmaf(hj, w_attn[j], av);
  }

  float attn = fmaxf(av, 0.f) + log1pf(expf(-fabsf(av)));   // softplus
  float dist = (lane < NS-1) ? (dval(lane+1) - dv) : 1e10f;
  float alpha = 1.0f - expf(-attn*dist);

  // inclusive multiplicative scan of (1-alpha+1e-6), shifted -> transmittance
  float fac = 1.0f - alpha + 1e-6f;
  float scan = fac;
  #pragma unroll
  for (int m=1; m<64; m<<=1){
    float up = __shfl_up(scan, m, 64);
    if (lane >= m) scan *= up;
  }
  float T = __shfl_up(scan, 1, 64);
  if (lane == 0) T = 1.0f;
  float wgt = T * alpha;

  float delf = fminf(fmaxf(rintf(sqrtf(dd2)*16000.0f/343.0f), 0.f), 511.f);

  const int bsid = b*NS + lane;
  const int o2 = bsid*RAYS + r;
  w_arr[o2] = wgt;
  delay_arr[o2] = (int)delf;

  // quartered store: quarter p -> [p][bsid][r][16] halves (32 B per quarter)
  #pragma unroll
  for (int p=0; p<SPLIT; p++){
    uint4 v0, v1;
    v0.x = pk2(wgt*h[p*16+ 0], wgt*h[p*16+ 1]);
    v0.y = pk2(wgt*h[p*16+ 2], wgt*h[p*16+ 3]);
    v0.z = pk2(wgt*h[p*16+ 4], wgt*h[p*16+ 5]);
    v0.w = pk2(wgt*h[p*16+ 6], wgt*h[p*16+ 7]);
    v1.x = pk2(wgt*h[p*16+ 8], wgt*h[p*16+ 9]);
    v1.y = pk2(wgt*h[p*16+10], wgt*h[p*16+11]);
    v1.z = pk2(wgt*h[p*16+12], wgt*h[p*16+13]);
    v1.w = pk2(wgt*h[p*16+14], wgt*h[p*16+15]);
    uint4* dst = (uint4*)(wh + (((size_t)p*BS*NS + bsid)*RAYS + r)*16);
    dst[0] = v0; dst[1] = v1;
  }
}

// K23 fused: per (bsid,p) block runs the R12 k2 body (scatter -> 3-pass scan
// -> split dot -> atomicAdd g), then fence + cnt[bsid]++. The LAST of the 4
// sibling blocks (no spinning; others exit) runs the full 512-pt DFT for this
// bsid with its 16 waves (4 grp x 4 l-chunk) + frac phase -> atomicAdd out.
__global__ __launch_bounds__(1024, 8)
void k23_fused(const __half* __restrict__ wh, const float* __restrict__ w_arr,
               const int* __restrict__ delay_arr,
               const float* __restrict__ W_sig, const float* __restrict__ b_sig,
               float* __restrict__ g, float* __restrict__ out, int* __restrict__ cnt)
{
  __shared__ __align__(16) char smem[43392];
  float (*bucket)[JC+1] = (float(*)[JC+1])smem;             // 34,816 B
  float (*part)[JC+1]   = (float(*)[JC+1])(smem + 34816);   //  4,352 B
  int*   delay_l = (int*)  (smem + 39168);                  //  2,056 B
  float* w_l     = (float*)(smem + 41224);                  //  2,056 B
  __shared__ int lastFlag;

  const int blk = blockIdx.x;
  const int bsid = blk / SPLIT, p = blk % SPLIT;
  const int tid = threadIdx.x;
  const int obase = bsid * RAYS;

  for (int i = tid; i < LSEQ*(JC+1); i += 1024) (&bucket[0][0])[i] = 0.f;
  if (tid < RAYS){
    delay_l[tid] = delay_arr[obase + tid];
    if (p == 0) w_l[tid] = w_arr[obase + tid];
  }
  __syncthreads();

  // scatter: 1028 uint4s, one sweep
  {
    const uint4* whp = (const uint4*)(wh + ((size_t)p*BS*NS + bsid)*RAYS*16);
    for (int idx = tid; idx < RAYS*2; idx += 1024){
      int r = idx >> 1, c8 = (idx & 1) << 3;
      uint4 v = whp[idx];
      int d = delay_l[r];
      float* brow = &bucket[d][c8];
      atomicAdd(&brow[0], __half2float(__ushort_as_half((ushort)(v.x & 0xFFFF))));
      atomicAdd(&brow[1], __half2float(__ushort_as_half((ushort)(v.x >> 16))));
      atomicAdd(&brow[2], __half2float(__ushort_as_half((ushort)(v.y & 0xFFFF))));
      atomicAdd(&brow[3], __half2float(__ushort_as_half((ushort)(v.y >> 16))));
      atomicAdd(&brow[4], __half2float(__ushort_as_half((ushort)(v.z & 0xFFFF))));
      atomicAdd(&brow[5], __half2float(__ushort_as_half((ushort)(v.z >> 16))));
      atomicAdd(&brow[6], __half2float(__ushort_as_half((ushort)(v.w & 0xFFFF))));
      atomicAdd(&brow[7], __half2float(__ushort_as_half((ushort)(v.w >> 16))));
      if (p == 0 && c8 == 0) atomicAdd(&bucket[d][JC], w_l[r]);
    }
  }
  __syncthreads();

  // pass 1: 64 segs x 8 rows inclusive scan; seg totals -> part
  const int seg = tid >> 4, col = tid & 15, d0 = seg*8;
  {
    float run = 0.f;
    #pragma unroll
    for (int k=0;k<8;k++){ run += bucket[d0+k][col]; bucket[d0+k][col] = run; }
    part[seg][col] = run;
    if (p == 0 && col == 15){
      float rw = 0.f;
      #pragma unroll
      for (int k=0;k<8;k++){ rw += bucket[d0+k][JC]; bucket[d0+k][JC] = rw; }
      part[seg][JC] = rw;
    }
  }
  __syncthreads();

  // pass 2: wave w scans part[:][w] via shfl_up; wave 15 also scans w-col
  {
    const int w = tid >> 6, lam = tid & 63;
    float v = part[lam][w];
    #pragma unroll
    for (int m=1;m<64;m<<=1){ float u = __shfl_up(v, m, 64); if (lam >= m) v += u; }
    part[lam][w] = v;
    if (w == 15 && p == 0){
      float vw = part[lam][JC];
      #pragma unroll
      for (int m=1;m<64;m<<=1){ float u = __shfl_up(vw, m, 64); if (lam >= m) vw += u; }
      part[lam][JC] = vw;
    }
  }
  __syncthreads();

  // pass 3: add exclusive segment offsets back
  {
    float off = (seg > 0) ? part[seg-1][col] : 0.f;
    #pragma unroll
    for (int k=0;k<8;k++) bucket[d0+k][col] += off;
    if (p == 0 && col == 15){
      float ow = (seg > 0) ? part[seg-1][JC] : 0.f;
      #pragma unroll
      for (int k=0;k<8;k++) bucket[d0+k][JC] += ow;
    }
  }
  __syncthreads();

  // dot + mask + path loss, split across thread halves; atomicAdd into g
  const int s = bsid % NS;
  const float dv = dval(s);
  {
    const float shiftf = rintf((16000.0f*dv)/343.0f);
    const int shift = (int)shiftf;
    const int jbase = p*JC;
    const int half = tid >> 9, l = tid & 511;
    float mt = (((float)(LSEQ-1-l)) - shiftf > 0.f) ? 1.f : 0.f;
    if (mt > 0.f){
      float acc = 0.f;
      const int j0 = half*8;
      #pragma unroll
      for (int jj=0;jj<8;jj++) acc += bucket[l][j0+jj] * W_sig[(jbase+j0+jj)*LSEQ + l];
      if (p == 0 && half == 1) acc += b_sig[l] * bucket[l][JC];
      int pli = shift + l;
      if (pli < 4) pli = 5;                     // path_loss[:4] = path_loss[5]
      float ideal = ((float)pli/16000.0f)*343.0f;
      atomicAdd(&g[bsid*LSEQ + l], acc / (ideal + 0.001f));
    }
  }

  // ---- arrival sync: last of the 4 sibling blocks does the DFT ----
  __threadfence();                 // release: drain our g atomics
  __syncthreads();
  if (tid == 0){
    int prev = __hip_atomic_fetch_add(&cnt[bsid], 1, __ATOMIC_ACQ_REL, __HIP_MEMORY_SCOPE_AGENT);
    lastFlag = (prev == SPLIT-1);
  }
  __syncthreads();
  if (!lastFlag) return;
  __threadfence();                 // acquire: see sibling blocks' g writes

  // ---- phase C: 512-pt DFT for this bsid (16 waves = 4 grp x 4 chunk) ----
  float4* gs4 = (float4*)smem;                    // 2,048 B (reuse)
  float*  red = (float*)(smem + 2048);            // 4*4*64*2*4 = 8,192 B
  __syncthreads();                                // all waves past bucket use

  if (tid < LSEQ/4) gs4[tid] = ((const float4*)(g + bsid*LSEQ))[tid];
  __syncthreads();

  const int w = tid >> 6, lane = tid & 63;
  const int grp = w >> 2, c = w & 3;
  const int b = bsid / NS;
  const int k = grp*64 + lane;
  {
    float s1, c1; sincosf(-(TWO_PI_F/512.0f)*(float)k, &s1, &c1);
    float c2 = c1*c1 - s1*s1,  s2 = 2.0f*c1*s1;
    float c3 = c1*c2 - s1*s2,  s3 = c1*s2 + s1*c2;
    float c4 = c2*c2 - s2*s2,  s4 = 2.0f*c2*s2;
    const int l0 = c*128;
    int t0 = (k*l0) & (LSEQ-1);
    float wi, wr; sincosf(-(TWO_PI_F/512.0f)*(float)t0, &wi, &wr);
    float re = 0.f, im = 0.f;
    for (int q=0; q<32; q++){
      float4 gv = gs4[c*32 + q];                 // wave-uniform broadcast
      float pr = gv.x + gv.y*c1 + gv.z*c2 + gv.w*c3;
      float pi =        gv.y*s1 + gv.z*s2 + gv.w*s3;
      re = fmaf(pr, wr, re); re = fmaf(-pi, wi, re);
      im = fmaf(pr, wi, im); im = fmaf( pi, wr, im);
      float nr = wr*c4 - wi*s4;
      wi = fmaf(wr, s4, wi*c4);
      wr = nr;
    }
    red[(((grp*4)+c)*64 + lane)*2    ] = re;
    red[(((grp*4)+c)*64 + lane)*2 + 1] = im;
  }
  __syncthreads();

  const float cfrac = (16000.0f*dv)/343.0f;       // fractional pts2rx_idx
  if (tid < 256){
    const int gg = tid >> 6, bl = tid & 63;
    const int kk = gg*64 + bl;
    float rs = 0.f, is = 0.f;
    #pragma unroll
    for (int cc=0; cc<4; cc++){
      rs += red[(((gg*4)+cc)*64 + bl)*2    ];
      is += red[(((gg*4)+cc)*64 + bl)*2 + 1];
    }
    float ang = -(TWO_PI_F/512.0f)*((float)kk*cfrac);
    float sp, cp; sincosf(ang, &sp, &cp);
    atomicAdd(&out[(b*NF + kk)*2],     rs*cp - is*sp);
    atomicAdd(&out[(b*NF + kk)*2 + 1], rs*sp + is*cp);
  } else if (tid < 320){
    // bin 256: alternating sum (exact, real); wave 4 lanes 0..63
    int t = tid - 256;
    float4 a = gs4[t], bq = gs4[t+64];
    float alt = (a.x - a.y + a.z - a.w) + (bq.x - bq.y + bq.z - bq.w);
    #pragma unroll
    for (int m=32; m>=1; m>>=1) alt += __shfl_xor(alt, m, 64);
    if (t == 0){
      float ang = -(TWO_PI_F/512.0f)*(256.0f*cfrac);
      float sp, cp; sincosf(ang, &sp, &cp);
      atomicAdd(&out[(b*NF + 256)*2],     alt*cp);
      atomicAdd(&out[(b*NF + 256)*2 + 1], alt*sp);
    }
  }
}

extern "C" void kernel_launch(void* const* d_in, const int* in_sizes, int n_in,
                              void* d_out, int out_size, void* d_ws, size_t ws_size,
                              hipStream_t stream)
{
  const float* rays_o      = (const float*)d_in[0];
  const float* position_tx = (const float*)d_in[1];
  const float* W1          = (const float*)d_in[2];
  const float* b1          = (const float*)d_in[3];
  const float* w_attn      = (const float*)d_in[4];
  const float* W_sig       = (const float*)d_in[5];
  const float* b_sig       = (const float*)d_in[6];
  float* out = (float*)d_out;

  // workspace layout (~9.2 MB total)
  char* ws = (char*)d_ws;
  __half* wh       = (__half*)ws;                               // 4*128*514*16*2B = 8,421,376
  float* w_arr     = (float*)(ws + 8421376);                    // 263,168
  int*   delay_arr = (int*)  (ws + 8421376 + 263168);           // 263,168
  float* g         = (float*)(ws + 8421376 + 2*263168);         // 262,144
  int*   cnt       = (int*)  (ws + 8421376 + 2*263168 + 262144);// 512 B

  k1_rays  <<<(BS*RAYS)/4,  256, 0, stream>>>(rays_o, position_tx, W1, b1, w_attn,
                                              wh, w_arr, delay_arr, g, out, cnt);
  k23_fused<<<BS*NS*SPLIT, 1024, 0, stream>>>(wh, w_arr, delay_arr, W_sig, b_sig,
                                              g, out, cnt);
}

// Round 14
// 55.675 us; speedup vs baseline: 5.1673x; 5.1673x over previous
//
#include <hip/hip_runtime.h>
#include <hip/hip_fp16.h>
#include <stdint.h>
#include <math.h>

#define BS    2
#define RAYS  514
#define NS    64
#define LSEQ  512
#define NF    257
#define HIDN  64
#define SPLIT 4
#define JC    16      // hidden columns per k2 block

#define TWO_PI_F 6.28318530717958647692f

__device__ __forceinline__ uint32_t rotl32(uint32_t x, int d){ return (x<<d)|(x>>(32-d)); }

__device__ __forceinline__ void tf_rounds4(uint32_t& x0, uint32_t& x1, int a, int b, int c, int d){
  x0+=x1; x1=rotl32(x1,a); x1^=x0;
  x0+=x1; x1=rotl32(x1,b); x1^=x0;
  x0+=x1; x1=rotl32(x1,c); x1^=x0;
  x0+=x1; x1=rotl32(x1,d); x1^=x0;
}

// Threefry-2x32, 20 rounds, matching jax._src.prng.threefry2x32
__device__ void threefry2x32(uint32_t k0, uint32_t k1, uint32_t x0, uint32_t x1,
                             uint32_t& o0, uint32_t& o1)
{
  const uint32_t ks2 = k0 ^ k1 ^ 0x1BD11BDAu;
  x0 += k0; x1 += k1;
  tf_rounds4(x0,x1,13,15,26,6);   x0+=k1;  x1+=ks2+1u;
  tf_rounds4(x0,x1,17,29,16,24);  x0+=ks2; x1+=k0+2u;
  tf_rounds4(x0,x1,13,15,26,6);   x0+=k0;  x1+=k1+3u;
  tf_rounds4(x0,x1,17,29,16,24);  x0+=k1;  x1+=ks2+4u;
  tf_rounds4(x0,x1,13,15,26,6);   x0+=ks2; x1+=k0+5u;
  o0 = x0; o1 = x1;
}

// Reproduces _ray_directions() for ray r (verified round 0).
__device__ void ray_dir(int r, float d[3])
{
  if (r >= 512) { d[0]=0.f; d[1]=0.f; d[2] = (r==512) ? 1.0f : -1.0f; return; }
  int i = r >> 4, j = r & 15;
  uint32_t o0, o1;
  threefry2x32(0u, 42u, 0u, (uint32_t)i, o0, o1);
  uint32_t bits = o0 ^ o1;
  float u = __uint_as_float((bits >> 9) | 0x3F800000u) - 1.0f;   // uniform [0,1)
  const float step = TWO_PI_F / 32.0f;
  float a = (float)i * step + step * u;
  float e = acosf(2.0f * ((float)(j+1) * (1.0f/17.0f)) - 1.0f);
  float se = sinf(e);
  d[0] = cosf(a) * se;
  d[1] = sinf(a) * se;
  d[2] = cosf(e);
}

__device__ __forceinline__ float dval(int s){ return ((float)s*(1.0f/63.0f))*7.9f + 0.1f; }

__device__ __forceinline__ uint32_t pk2(float a, float b){
  return (uint32_t)__half_as_ushort(__float2half(a)) |
         ((uint32_t)__half_as_ushort(__float2half(b)) << 16);
}

// K1: R10 proven form (4 waves/block, one (b,r) per wave; lane = s).
__global__ __launch_bounds__(256)
void k1_rays(const float* __restrict__ rays_o, const float* __restrict__ position_tx,
             const float* __restrict__ W1, const float* __restrict__ b1,
             const float* __restrict__ w_attn,
             __half* __restrict__ wh, float* __restrict__ w_arr, int* __restrict__ delay_arr,
             float* __restrict__ g, float* __restrict__ out)
{
  const int tid = threadIdx.x;
  const int wid = tid >> 6, lane = tid & 63;       // lane = s index
  const int br = blockIdx.x*4 + wid;               // 257*4 = 1028 = BS*RAYS
  const int b = br / RAYS, r = br % RAYS;

  { // zero the atomic accumulators (65792 threads cover g:65536 and out:1028)
    int gi = blockIdx.x*256 + tid;
    if (gi < BS*NS*LSEQ) g[gi] = 0.f;
    if (gi < BS*NF*2) out[gi] = 0.f;
  }

  float dir[3]; ray_dir(r, dir);
  const float mn[3] = {-5.f,-5.f,-3.f}, mx[3] = {5.f,5.f,3.f};
  float ro[3], ntx[3];
  #pragma unroll
  for (int c=0;c<3;c++){
    ro[c] = rays_o[b*3+c];
    float t = position_tx[b*3+c];
    ntx[c] = 2.0f*(t - mn[c])/(mx[c]-mn[c]) - 1.0f;
  }

  const float dv = dval(lane);
  float feat[9], dd2 = 0.f;
  #pragma unroll
  for (int c=0;c<3;c++){
    float pt = ro[c] + dir[c]*dv;
    float npt = 2.0f*(pt - mn[c])/(mx[c]-mn[c]) - 1.0f;
    float ddc = ((ntx[c]-npt) + 1.0f)/2.0f*(mx[c]-mn[c]) + mn[c];
    dd2 += ddc*ddc;
    feat[c]   = npt;
    feat[3+c] = -dir[c];
    feat[6+c] = ntx[c];
  }

  float h[HIDN];
  float av = 0.f;
  #pragma unroll
  for (int j=0; j<HIDN; j++){
    float hj = b1[j];
    #pragma unroll
    for (int f=0; f<9; f++) hj = fmaf(feat[f], W1[f*HIDN + j], hj);
    hj = fmaxf(hj, 0.0f);
    h[j] = hj;
    av = fmaf(hj, w_attn[j], av);
  }

  float attn = fmaxf(av, 0.f) + log1pf(expf(-fabsf(av)));   // softplus
  float dist = (lane < NS-1) ? (dval(lane+1) - dv) : 1e10f;
  float alpha = 1.0f - expf(-attn*dist);

  // inclusive multiplicative scan of (1-alpha+1e-6), shifted -> transmittance
  float fac = 1.0f - alpha + 1e-6f;
  float scan = fac;
  #pragma unroll
  for (int m=1; m<64; m<<=1){
    float up = __shfl_up(scan, m, 64);
    if (lane >= m) scan *= up;
  }
  float T = __shfl_up(scan, 1, 64);
  if (lane == 0) T = 1.0f;
  float wgt = T * alpha;

  float delf = fminf(fmaxf(rintf(sqrtf(dd2)*16000.0f/343.0f), 0.f), 511.f);

  const int bsid = b*NS + lane;
  const int o2 = bsid*RAYS + r;
  w_arr[o2] = wgt;
  delay_arr[o2] = (int)delf;

  // quartered store: quarter p -> [p][bsid][r][16] halves (32 B per quarter)
  #pragma unroll
  for (int p=0; p<SPLIT; p++){
    uint4 v0, v1;
    v0.x = pk2(wgt*h[p*16+ 0], wgt*h[p*16+ 1]);
    v0.y = pk2(wgt*h[p*16+ 2], wgt*h[p*16+ 3]);
    v0.z = pk2(wgt*h[p*16+ 4], wgt*h[p*16+ 5]);
    v0.w = pk2(wgt*h[p*16+ 6], wgt*h[p*16+ 7]);
    v1.x = pk2(wgt*h[p*16+ 8], wgt*h[p*16+ 9]);
    v1.y = pk2(wgt*h[p*16+10], wgt*h[p*16+11]);
    v1.z = pk2(wgt*h[p*16+12], wgt*h[p*16+13]);
    v1.w = pk2(wgt*h[p*16+14], wgt*h[p*16+15]);
    uint4* dst = (uint4*)(wh + (((size_t)p*BS*NS + bsid)*RAYS + r)*16);
    dst[0] = v0; dst[1] = v1;
  }
}

// K2 v5: delay-RANGE-narrowed bucket. Per block: compute [dmin,dmax] of the
// 514 delays (shfl reduce + LDS atomics), then zero/scan/dot ONLY that span.
// l>dmax uses column totals via LDS broadcast; l<dmin contributes exactly 0
// (skipped, incl. the g atomic). Scatter unchanged (R10 form). This cuts the
// LDS op count ~2.5x on zero+scan+dot (DS-pipe-throughput hypothesis).
__global__ __launch_bounds__(512)
void k2_bucket(const __half* __restrict__ wh, const float* __restrict__ w_arr,
               const int* __restrict__ delay_arr,
               const float* __restrict__ W_sig, const float* __restrict__ b_sig,
               float* __restrict__ g)
{
  __shared__ float bucket[LSEQ][JC+1];   // col 16 = w column; 34,816 B
  __shared__ float part[32][JC+1];       // 2,176 B
  __shared__ int   delay_l[RAYS];        // 2,056 B
  __shared__ float w_l[RAYS];            // 2,056 B
  __shared__ int   dmm[2];               // 8 B   (total ~41.1 KB)
  const int blk = blockIdx.x;
  const int bsid = blk / SPLIT, p = blk % SPLIT;
  const int tid = threadIdx.x;
  const int lane = tid & 63;
  const int obase = bsid * RAYS;

  if (tid == 0){ dmm[0] = 0x7fffffff; dmm[1] = -1; }
  int dmn = 0x7fffffff, dmx = -1;
  for (int i = tid; i < RAYS; i += 512){
    int d = delay_arr[obase + i];
    delay_l[i] = d;
    dmn = min(dmn, d); dmx = max(dmx, d);
    if (p == 0) w_l[i] = w_arr[obase + i];
  }
  #pragma unroll
  for (int m = 32; m >= 1; m >>= 1){
    dmn = min(dmn, __shfl_xor(dmn, m, 64));
    dmx = max(dmx, __shfl_xor(dmx, m, 64));
  }
  __syncthreads();                       // dmm init + delay_l visible
  if (lane == 0){ atomicMin(&dmm[0], dmn); atomicMax(&dmm[1], dmx); }
  __syncthreads();
  const int dmin = dmm[0], dmax = dmm[1];
  const int span = dmax - dmin + 1;

  // zero only the active rows [dmin..dmax]
  {
    float* bz = &bucket[dmin][0];
    for (int i = tid; i < span*(JC+1); i += 512) bz[i] = 0.f;
  }
  __syncthreads();

  // scatter: 1028 uint4s (2 per ray), 3 coalesced sweeps; 8 LDS atomics each
  {
    const uint4* whp = (const uint4*)(wh + ((size_t)p*BS*NS + bsid)*RAYS*16);
    #pragma unroll
    for (int i=0; i<3; i++){
      int idx = i*512 + tid;
      if (idx < RAYS*2){
        int r = idx >> 1, c8 = (idx & 1) << 3;
        uint4 v = whp[idx];
        int d = delay_l[r];
        float* brow = &bucket[d][c8];
        atomicAdd(&brow[0], __half2float(__ushort_as_half((ushort)(v.x & 0xFFFF))));
        atomicAdd(&brow[1], __half2float(__ushort_as_half((ushort)(v.x >> 16))));
        atomicAdd(&brow[2], __half2float(__ushort_as_half((ushort)(v.y & 0xFFFF))));
        atomicAdd(&brow[3], __half2float(__ushort_as_half((ushort)(v.y >> 16))));
        atomicAdd(&brow[4], __half2float(__ushort_as_half((ushort)(v.z & 0xFFFF))));
        atomicAdd(&brow[5], __half2float(__ushort_as_half((ushort)(v.z >> 16))));
        atomicAdd(&brow[6], __half2float(__ushort_as_half((ushort)(v.w & 0xFFFF))));
        atomicAdd(&brow[7], __half2float(__ushort_as_half((ushort)(v.w >> 16))));
        if (p == 0 && c8 == 0) atomicAdd(&bucket[d][JC], w_l[r]);
      }
    }
  }
  __syncthreads();

  // scan over [dmin..dmax]: 32 segs x rps rows
  const int rps = (span + 31) >> 5;
  const int seg = tid >> 4, col = tid & 15;
  {
    const int r0 = dmin + seg*rps;
    const int re = min(rps, dmax + 1 - r0);
    float run = 0.f;
    for (int k = 0; k < re; k++){ run += bucket[r0+k][col]; bucket[r0+k][col] = run; }
    part[seg][col] = run;                  // 0 for empty segs
    if (p == 0 && col == 15){
      float rw = 0.f;
      for (int k = 0; k < re; k++){ rw += bucket[r0+k][JC]; bucket[r0+k][JC] = rw; }
      part[seg][JC] = rw;
    }
  }
  __syncthreads();

  // pass 2: 8 waves; wave w scans cols w and w+8 (32 segs) via width-32 shfl
  {
    const int w = tid >> 6;
    if (lane < 32){
      float v1 = part[lane][w], v2 = part[lane][w+8];
      #pragma unroll
      for (int m=1; m<32; m<<=1){
        float u1 = __shfl_up(v1, m, 32);
        float u2 = __shfl_up(v2, m, 32);
        if (lane >= m){ v1 += u1; v2 += u2; }
      }
      part[lane][w] = v1; part[lane][w+8] = v2;
      if (w == 7 && p == 0){
        float vw = part[lane][JC];
        #pragma unroll
        for (int m=1; m<32; m<<=1){
          float uw = __shfl_up(vw, m, 32);
          if (lane >= m) vw += uw;
        }
        part[lane][JC] = vw;
      }
    }
  }
  __syncthreads();

  // pass 3: add exclusive segment offsets back
  {
    const int r0 = dmin + seg*rps;
    const int re = min(rps, dmax + 1 - r0);
    float off = (seg > 0) ? part[seg-1][col] : 0.f;
    for (int k = 0; k < re; k++) bucket[r0+k][col] += off;
    if (p == 0 && col == 15){
      float ow = (seg > 0) ? part[seg-1][JC] : 0.f;
      for (int k = 0; k < re; k++) bucket[r0+k][JC] += ow;
    }
  }
  __syncthreads();

  // dot + mask + path loss -> atomicAdd into g[bsid][l]  (one l per thread)
  // l < dmin: exactly zero -> skip. l > dmax: column totals part[31][*]
  // via same-address LDS broadcast (conflict-free).
  const int s = bsid % NS;
  const float dv = dval(s);
  const float shiftf = rintf((16000.0f*dv)/343.0f);
  const int shift = (int)shiftf;
  const int jbase = p*JC;
  {
    const int l = tid;
    float mt = (((float)(LSEQ-1-l)) - shiftf > 0.f) ? 1.f : 0.f;
    if (mt > 0.f && l >= dmin){
      float acc = 0.f;
      if (l <= dmax){
        #pragma unroll
        for (int jj=0;jj<JC;jj++) acc += bucket[l][jj] * W_sig[(jbase+jj)*LSEQ + l];
        if (p == 0) acc += b_sig[l] * bucket[l][JC];
      } else {
        #pragma unroll
        for (int jj=0;jj<JC;jj++) acc += part[31][jj] * W_sig[(jbase+jj)*LSEQ + l];
        if (p == 0) acc += b_sig[l] * part[31][JC];
      }
      int pli = shift + l;
      if (pli < 4) pli = 5;                     // path_loss[:4] = path_loss[5]
      float ideal = ((float)pli/16000.0f)*343.0f;
      atomicAdd(&g[bsid*LSEQ + l], acc / (ideal + 0.001f));
    }
  }
}

// K3: unchanged from round 10 (cubic-factorized register-twiddle DFT).
__global__ __launch_bounds__(256)
void k3_dft(const float* __restrict__ g, float* __restrict__ out)
{
  __shared__ float4 gs4[LSEQ/4];
  __shared__ float red[4][64][2];
  const int blk = blockIdx.x;
  const int bsid = blk >> 2, grp = blk & 3;
  const int b = bsid / NS, s = bsid % NS;
  const int tid = threadIdx.x;
  const int c = tid >> 6, bl = tid & 63;         // c = l-chunk wave, bl = bin

  if (tid < LSEQ/4) gs4[tid] = ((const float4*)(g + bsid*LSEQ))[tid];
  __syncthreads();

  const int k = grp*64 + bl;
  float re = 0.f, im = 0.f;
  {
    float s1, c1; sincosf(-(TWO_PI_F/512.0f)*(float)k, &s1, &c1);
    float c2 = c1*c1 - s1*s1,  s2 = 2.0f*c1*s1;
    float c3 = c1*c2 - s1*s2,  s3 = c1*s2 + s1*c2;
    float c4 = c2*c2 - s2*s2,  s4 = 2.0f*c2*s2;
    const int l0 = c*128;
    int t0 = (k*l0) & (LSEQ-1);
    float wi, wr; sincosf(-(TWO_PI_F/512.0f)*(float)t0, &wi, &wr);
    for (int q=0; q<32; q++){
      float4 gv = gs4[c*32 + q];                 // wave-uniform broadcast
      float pr = gv.x + gv.y*c1 + gv.z*c2 + gv.w*c3;
      float pi =        gv.y*s1 + gv.z*s2 + gv.w*s3;
      re = fmaf(pr, wr, re); re = fmaf(-pi, wi, re);
      im = fmaf(pr, wi, im); im = fmaf( pi, wr, im);
      float nr = wr*c4 - wi*s4;
      wi = fmaf(wr, s4, wi*c4);
      wr = nr;
    }
  }
  red[c][bl][0] = re; red[c][bl][1] = im;
  __syncthreads();

  const float cfrac = (16000.0f*dval(s))/343.0f; // fractional pts2rx_idx
  if (tid < 64){
    const int kk = grp*64 + tid;
    float rs = red[0][tid][0] + red[1][tid][0] + red[2][tid][0] + red[3][tid][0];
    float is = red[0][tid][1] + red[1][tid][1] + red[2][tid][1] + red[3][tid][1];
    float ang = -(TWO_PI_F/512.0f)*((float)kk*cfrac);
    float sp, cp; sincosf(ang, &sp, &cp);
    atomicAdd(&out[(b*NF + kk)*2],     rs*cp - is*sp);
    atomicAdd(&out[(b*NF + kk)*2 + 1], rs*sp + is*cp);
  } else if (grp == 0 && tid < 128){
    int t = tid - 64;
    float4 a = gs4[t], bq = gs4[t+64];
    float alt = (a.x - a.y + a.z - a.w) + (bq.x - bq.y + bq.z - bq.w);
    #pragma unroll
    for (int m=32; m>=1; m>>=1) alt += __shfl_xor(alt, m, 64);
    if (t == 0){
      float ang = -(TWO_PI_F/512.0f)*(256.0f*cfrac);
      float sp, cp; sincosf(ang, &sp, &cp);
      atomicAdd(&out[(b*NF + 256)*2],     alt*cp);
      atomicAdd(&out[(b*NF + 256)*2 + 1], alt*sp);
    }
  }
}

extern "C" void kernel_launch(void* const* d_in, const int* in_sizes, int n_in,
                              void* d_out, int out_size, void* d_ws, size_t ws_size,
                              hipStream_t stream)
{
  const float* rays_o      = (const float*)d_in[0];
  const float* position_tx = (const float*)d_in[1];
  const float* W1          = (const float*)d_in[2];
  const float* b1          = (const float*)d_in[3];
  const float* w_attn      = (const float*)d_in[4];
  const float* W_sig       = (const float*)d_in[5];
  const float* b_sig       = (const float*)d_in[6];
  float* out = (float*)d_out;

  // workspace layout (~9.2 MB total)
  char* ws = (char*)d_ws;
  __half* wh       = (__half*)ws;                               // 4*128*514*16*2B = 8,421,376
  float* w_arr     = (float*)(ws + 8421376);                    // 263,168
  int*   delay_arr = (int*)  (ws + 8421376 + 263168);           // 263,168
  float* g         = (float*)(ws + 8421376 + 2*263168);         // 262,144

  k1_rays  <<<(BS*RAYS)/4,  256, 0, stream>>>(rays_o, position_tx, W1, b1, w_attn,
                                              wh, w_arr, delay_arr, g, out);
  k2_bucket<<<BS*NS*SPLIT,  512, 0, stream>>>(wh, w_arr, delay_arr, W_sig, b_sig, g);
  k3_dft   <<<BS*NS*4,      256, 0, stream>>>(g, out);
}

// Round 15
// 34.456 us; speedup vs baseline: 8.3495x; 1.6158x over previous
//
#include <hip/hip_runtime.h>
#include <hip/hip_fp16.h>
#include <stdint.h>
#include <math.h>

#define BS    2
#define RAYS  514
#define NS    64
#define LSEQ  512
#define NF    257
#define HIDN  64
#define SPLIT 4
#define JC    16      // hidden columns per k2 block

#define TWO_PI_F 6.28318530717958647692f

__device__ __forceinline__ uint32_t rotl32(uint32_t x, int d){ return (x<<d)|(x>>(32-d)); }

__device__ __forceinline__ void tf_rounds4(uint32_t& x0, uint32_t& x1, int a, int b, int c, int d){
  x0+=x1; x1=rotl32(x1,a); x1^=x0;
  x0+=x1; x1=rotl32(x1,b); x1^=x0;
  x0+=x1; x1=rotl32(x1,c); x1^=x0;
  x0+=x1; x1=rotl32(x1,d); x1^=x0;
}

// Threefry-2x32, 20 rounds, matching jax._src.prng.threefry2x32
__device__ void threefry2x32(uint32_t k0, uint32_t k1, uint32_t x0, uint32_t x1,
                             uint32_t& o0, uint32_t& o1)
{
  const uint32_t ks2 = k0 ^ k1 ^ 0x1BD11BDAu;
  x0 += k0; x1 += k1;
  tf_rounds4(x0,x1,13,15,26,6);   x0+=k1;  x1+=ks2+1u;
  tf_rounds4(x0,x1,17,29,16,24);  x0+=ks2; x1+=k0+2u;
  tf_rounds4(x0,x1,13,15,26,6);   x0+=k0;  x1+=k1+3u;
  tf_rounds4(x0,x1,17,29,16,24);  x0+=k1;  x1+=ks2+4u;
  tf_rounds4(x0,x1,13,15,26,6);   x0+=ks2; x1+=k0+5u;
  o0 = x0; o1 = x1;
}

// Reproduces _ray_directions() for ray r (verified round 0).
__device__ void ray_dir(int r, float d[3])
{
  if (r >= 512) { d[0]=0.f; d[1]=0.f; d[2] = (r==512) ? 1.0f : -1.0f; return; }
  int i = r >> 4, j = r & 15;
  uint32_t o0, o1;
  threefry2x32(0u, 42u, 0u, (uint32_t)i, o0, o1);
  uint32_t bits = o0 ^ o1;
  float u = __uint_as_float((bits >> 9) | 0x3F800000u) - 1.0f;   // uniform [0,1)
  const float step = TWO_PI_F / 32.0f;
  float a = (float)i * step + step * u;
  float e = acosf(2.0f * ((float)(j+1) * (1.0f/17.0f)) - 1.0f);
  float se = sinf(e);
  d[0] = cosf(a) * se;
  d[1] = sinf(a) * se;
  d[2] = cosf(e);
}

__device__ __forceinline__ float dval(int s){ return ((float)s*(1.0f/63.0f))*7.9f + 0.1f; }

__device__ __forceinline__ uint32_t pk2(float a, float b){
  return (uint32_t)__half_as_ushort(__float2half(a)) |
         ((uint32_t)__half_as_ushort(__float2half(b)) << 16);
}

// K1: R10 proven form (4 waves/block, one (b,r) per wave; lane = s).
__global__ __launch_bounds__(256)
void k1_rays(const float* __restrict__ rays_o, const float* __restrict__ position_tx,
             const float* __restrict__ W1, const float* __restrict__ b1,
             const float* __restrict__ w_attn,
             __half* __restrict__ wh, float* __restrict__ w_arr, int* __restrict__ delay_arr,
             float* __restrict__ g, float* __restrict__ out)
{
  const int tid = threadIdx.x;
  const int wid = tid >> 6, lane = tid & 63;       // lane = s index
  const int br = blockIdx.x*4 + wid;               // 257*4 = 1028 = BS*RAYS
  const int b = br / RAYS, r = br % RAYS;

  { // zero the atomic accumulators (65792 threads cover g:65536 and out:1028)
    int gi = blockIdx.x*256 + tid;
    if (gi < BS*NS*LSEQ) g[gi] = 0.f;
    if (gi < BS*NF*2) out[gi] = 0.f;
  }

  float dir[3]; ray_dir(r, dir);
  const float mn[3] = {-5.f,-5.f,-3.f}, mx[3] = {5.f,5.f,3.f};
  float ro[3], ntx[3];
  #pragma unroll
  for (int c=0;c<3;c++){
    ro[c] = rays_o[b*3+c];
    float t = position_tx[b*3+c];
    ntx[c] = 2.0f*(t - mn[c])/(mx[c]-mn[c]) - 1.0f;
  }

  const float dv = dval(lane);
  float feat[9], dd2 = 0.f;
  #pragma unroll
  for (int c=0;c<3;c++){
    float pt = ro[c] + dir[c]*dv;
    float npt = 2.0f*(pt - mn[c])/(mx[c]-mn[c]) - 1.0f;
    float ddc = ((ntx[c]-npt) + 1.0f)/2.0f*(mx[c]-mn[c]) + mn[c];
    dd2 += ddc*ddc;
    feat[c]   = npt;
    feat[3+c] = -dir[c];
    feat[6+c] = ntx[c];
  }

  float h[HIDN];
  float av = 0.f;
  #pragma unroll
  for (int j=0; j<HIDN; j++){
    float hj = b1[j];
    #pragma unroll
    for (int f=0; f<9; f++) hj = fmaf(feat[f], W1[f*HIDN + j], hj);
    hj = fmaxf(hj, 0.0f);
    h[j] = hj;
    av = fmaf(hj, w_attn[j], av);
  }

  float attn = fmaxf(av, 0.f) + log1pf(expf(-fabsf(av)));   // softplus
  float dist = (lane < NS-1) ? (dval(lane+1) - dv) : 1e10f;
  float alpha = 1.0f - expf(-attn*dist);

  // inclusive multiplicative scan of (1-alpha+1e-6), shifted -> transmittance
  float fac = 1.0f - alpha + 1e-6f;
  float scan = fac;
  #pragma unroll
  for (int m=1; m<64; m<<=1){
    float up = __shfl_up(scan, m, 64);
    if (lane >= m) scan *= up;
  }
  float T = __shfl_up(scan, 1, 64);
  if (lane == 0) T = 1.0f;
  float wgt = T * alpha;

  float delf = fminf(fmaxf(rintf(sqrtf(dd2)*16000.0f/343.0f), 0.f), 511.f);

  const int bsid = b*NS + lane;
  const int o2 = bsid*RAYS + r;
  w_arr[o2] = wgt;
  delay_arr[o2] = (int)delf;

  // quartered store: quarter p -> [p][bsid][r][16] halves (32 B per quarter)
  #pragma unroll
  for (int p=0; p<SPLIT; p++){
    uint4 v0, v1;
    v0.x = pk2(wgt*h[p*16+ 0], wgt*h[p*16+ 1]);
    v0.y = pk2(wgt*h[p*16+ 2], wgt*h[p*16+ 3]);
    v0.z = pk2(wgt*h[p*16+ 4], wgt*h[p*16+ 5]);
    v0.w = pk2(wgt*h[p*16+ 6], wgt*h[p*16+ 7]);
    v1.x = pk2(wgt*h[p*16+ 8], wgt*h[p*16+ 9]);
    v1.y = pk2(wgt*h[p*16+10], wgt*h[p*16+11]);
    v1.z = pk2(wgt*h[p*16+12], wgt*h[p*16+13]);
    v1.w = pk2(wgt*h[p*16+14], wgt*h[p*16+15]);
    uint4* dst = (uint4*)(wh + (((size_t)p*BS*NS + bsid)*RAYS + r)*16);
    dst[0] = v0; dst[1] = v1;
  }
}

// K2 v6: COUNTING-SORT formulation — zero f32 LDS atomics.
// (1) int histogram of delays (2) shfl scan -> cum (3) per-ray rank via
// ds_add_rtn on exclusive counters (4) permute wh into sorted order (plain
// ds_write) (5) 3-pass prefix over sorted rows (no bucket zeroing needed)
// (6) dot reads P[cum[l]-1][*] (broadcast). Hcum[l][j] = P[cum[l]-1][j] exactly.
__global__ __launch_bounds__(512)
void k2_bucket(const __half* __restrict__ wh, const float* __restrict__ w_arr,
               const int* __restrict__ delay_arr,
               const float* __restrict__ W_sig, const float* __restrict__ b_sig,
               float* __restrict__ g)
{
  __shared__ __align__(16) ushort sorted_h[RAYS*16];   // 16,448 B
  __shared__ float  sorted_w[RAYS];                    //  2,056 B
  __shared__ float  P[RAYS][JC+1];                     // 34,952 B
  __shared__ float  part[32][JC+1];                    //  2,176 B (posbuf alias)
  __shared__ int    hist[LSEQ];                        //  2,048 B
  __shared__ int    cum[LSEQ];                         //  2,048 B
  __shared__ int    delay_l[RAYS];                     //  2,056 B
  __shared__ float  w_l[RAYS];                         //  2,056 B
  __shared__ int    wtot[8];                           //     32 B (~63.9 KB)

  const int blk = blockIdx.x;
  const int bsid = blk / SPLIT, p = blk % SPLIT;
  const int tid = threadIdx.x;
  const int wv = tid >> 6, lane = tid & 63;
  const int obase = bsid * RAYS;
  int* posbuf = (int*)&part[0][0];                     // 514 ints fit in 2,176 B

  // phase 1: load delays/w, zero histogram
  hist[tid] = 0;
  for (int i = tid; i < RAYS; i += 512){
    delay_l[i] = delay_arr[obase + i];
    if (p == 0) w_l[i] = w_arr[obase + i];
  }
  __syncthreads();

  // phase 2: histogram (int LDS atomics, 514 lane-ops)
  for (int i = tid; i < RAYS; i += 512) atomicAdd(&hist[delay_l[i]], 1);
  __syncthreads();

  // phase 3: inclusive scan of hist -> cum; hist -> exclusive base (in place)
  int h0 = hist[tid];
  {
    int v = h0;
    #pragma unroll
    for (int m=1; m<64; m<<=1){ int u = __shfl_up(v, m, 64); if (lane >= m) v += u; }
    if (lane == 63) wtot[wv] = v;
    __syncthreads();
    int off = 0;
    for (int t=0; t<wv; t++) off += wtot[t];
    int cumv = v + off;
    cum[tid] = cumv;
    hist[tid] = cumv - h0;                 // exclusive base = rank counter seed
  }
  __syncthreads();

  // phase 4a: per-ray position (one ds_add_rtn per ray)
  for (int i = tid; i < RAYS; i += 512)
    posbuf[i] = atomicAdd(&hist[delay_l[i]], 1);
  __syncthreads();

  // phase 4b: permute wh into sorted order (coalesced global -> plain ds_write)
  {
    const uint4* whp = (const uint4*)(wh + ((size_t)p*BS*NS + bsid)*RAYS*16);
    uint4* s4 = (uint4*)sorted_h;
    for (int idx = tid; idx < RAYS*2; idx += 512){
      int r = idx >> 1, half = idx & 1;
      uint4 v = whp[idx];
      s4[posbuf[r]*2 + half] = v;
    }
    if (p == 0)
      for (int i = tid; i < RAYS; i += 512) sorted_w[posbuf[i]] = w_l[i];
  }
  __syncthreads();

  // phase 5: prefix pass 1 — 31 segs x 17 rows over sorted data -> P
  const int seg = tid >> 4, col = tid & 15;
  const int r0 = seg*17;
  const int re = max(0, min(17, RAYS - r0));
  {
    float run = 0.f;
    for (int k=0; k<re; k++){
      run += __half2float(__ushort_as_half(sorted_h[(r0+k)*16 + col]));
      P[r0+k][col] = run;
    }
    part[seg][col] = run;                  // 0 for empty segs
    if (p == 0 && col == 15){
      float rw = 0.f;
      for (int k=0; k<re; k++){ rw += sorted_w[r0+k]; P[r0+k][JC] = rw; }
      part[seg][JC] = rw;
    }
  }
  __syncthreads();

  // phase 6: pass 2 — 8 waves; wave w scans part cols w and w+8 via shfl
  if (lane < 32){
    float v1 = part[lane][wv], v2 = part[lane][wv+8];
    #pragma unroll
    for (int m=1; m<32; m<<=1){
      float u1 = __shfl_up(v1, m, 32);
      float u2 = __shfl_up(v2, m, 32);
      if (lane >= m){ v1 += u1; v2 += u2; }
    }
    part[lane][wv] = v1; part[lane][wv+8] = v2;
    if (wv == 7 && p == 0){
      float vw = part[lane][JC];
      #pragma unroll
      for (int m=1; m<32; m<<=1){
        float uw = __shfl_up(vw, m, 32);
        if (lane >= m) vw += uw;
      }
      part[lane][JC] = vw;
    }
  }
  __syncthreads();

  // phase 7: pass 3 — add exclusive segment offsets back
  {
    float off = (seg > 0) ? part[seg-1][col] : 0.f;
    for (int k=0; k<re; k++) P[r0+k][col] += off;
    if (p == 0 && col == 15){
      float ow = (seg > 0) ? part[seg-1][JC] : 0.f;
      for (int k=0; k<re; k++) P[r0+k][JC] += ow;
    }
  }
  __syncthreads();

  // phase 8: dot + mask + path loss -> atomicAdd into g[bsid][l]
  const int s = bsid % NS;
  const float dv = dval(s);
  const float shiftf = rintf((16000.0f*dv)/343.0f);
  const int shift = (int)shiftf;
  const int jbase = p*JC;
  {
    const int l = tid;
    float mt = (((float)(LSEQ-1-l)) - shiftf > 0.f) ? 1.f : 0.f;
    const int c = cum[l];                  // # rays with delay <= l
    if (mt > 0.f && c > 0){
      const int row = c - 1;
      float acc = 0.f;
      #pragma unroll
      for (int jj=0;jj<JC;jj++) acc += P[row][jj] * W_sig[(jbase+jj)*LSEQ + l];
      if (p == 0) acc += b_sig[l] * P[row][JC];
      int pli = shift + l;
      if (pli < 4) pli = 5;                // path_loss[:4] = path_loss[5]
      float ideal = ((float)pli/16000.0f)*343.0f;
      atomicAdd(&g[bsid*LSEQ + l], acc / (ideal + 0.001f));
    }
  }
}

// K3: unchanged from round 10 (cubic-factorized register-twiddle DFT).
__global__ __launch_bounds__(256)
void k3_dft(const float* __restrict__ g, float* __restrict__ out)
{
  __shared__ float4 gs4[LSEQ/4];
  __shared__ float red[4][64][2];
  const int blk = blockIdx.x;
  const int bsid = blk >> 2, grp = blk & 3;
  const int b = bsid / NS, s = bsid % NS;
  const int tid = threadIdx.x;
  const int c = tid >> 6, bl = tid & 63;         // c = l-chunk wave, bl = bin

  if (tid < LSEQ/4) gs4[tid] = ((const float4*)(g + bsid*LSEQ))[tid];
  __syncthreads();

  const int k = grp*64 + bl;
  float re = 0.f, im = 0.f;
  {
    float s1, c1; sincosf(-(TWO_PI_F/512.0f)*(float)k, &s1, &c1);
    float c2 = c1*c1 - s1*s1,  s2 = 2.0f*c1*s1;
    float c3 = c1*c2 - s1*s2,  s3 = c1*s2 + s1*c2;
    float c4 = c2*c2 - s2*s2,  s4 = 2.0f*c2*s2;
    const int l0 = c*128;
    int t0 = (k*l0) & (LSEQ-1);
    float wi, wr; sincosf(-(TWO_PI_F/512.0f)*(float)t0, &wi, &wr);
    for (int q=0; q<32; q++){
      float4 gv = gs4[c*32 + q];                 // wave-uniform broadcast
      float pr = gv.x + gv.y*c1 + gv.z*c2 + gv.w*c3;
      float pi =        gv.y*s1 + gv.z*s2 + gv.w*s3;
      re = fmaf(pr, wr, re); re = fmaf(-pi, wi, re);
      im = fmaf(pr, wi, im); im = fmaf( pi, wr, im);
      float nr = wr*c4 - wi*s4;
      wi = fmaf(wr, s4, wi*c4);
      wr = nr;
    }
  }
  red[c][bl][0] = re; red[c][bl][1] = im;
  __syncthreads();

  const float cfrac = (16000.0f*dval(s))/343.0f; // fractional pts2rx_idx
  if (tid < 64){
    const int kk = grp*64 + tid;
    float rs = red[0][tid][0] + red[1][tid][0] + red[2][tid][0] + red[3][tid][0];
    float is = red[0][tid][1] + red[1][tid][1] + red[2][tid][1] + red[3][tid][1];
    float ang = -(TWO_PI_F/512.0f)*((float)kk*cfrac);
    float sp, cp; sincosf(ang, &sp, &cp);
    atomicAdd(&out[(b*NF + kk)*2],     rs*cp - is*sp);
    atomicAdd(&out[(b*NF + kk)*2 + 1], rs*sp + is*cp);
  } else if (grp == 0 && tid < 128){
    int t = tid - 64;
    float4 a = gs4[t], bq = gs4[t+64];
    float alt = (a.x - a.y + a.z - a.w) + (bq.x - bq.y + bq.z - bq.w);
    #pragma unroll
    for (int m=32; m>=1; m>>=1) alt += __shfl_xor(alt, m, 64);
    if (t == 0){
      float ang = -(TWO_PI_F/512.0f)*(256.0f*cfrac);
      float sp, cp; sincosf(ang, &sp, &cp);
      atomicAdd(&out[(b*NF + 256)*2],     alt*cp);
      atomicAdd(&out[(b*NF + 256)*2 + 1], alt*sp);
    }
  }
}

extern "C" void kernel_launch(void* const* d_in, const int* in_sizes, int n_in,
                              void* d_out, int out_size, void* d_ws, size_t ws_size,
                              hipStream_t stream)
{
  const float* rays_o      = (const float*)d_in[0];
  const float* position_tx = (const float*)d_in[1];
  const float* W1          = (const float*)d_in[2];
  const float* b1          = (const float*)d_in[3];
  const float* w_attn      = (const float*)d_in[4];
  const float* W_sig       = (const float*)d_in[5];
  const float* b_sig       = (const float*)d_in[6];
  float* out = (float*)d_out;

  // workspace layout (~9.2 MB total)
  char* ws = (char*)d_ws;
  __half* wh       = (__half*)ws;                               // 4*128*514*16*2B = 8,421,376
  float* w_arr     = (float*)(ws + 8421376);                    // 263,168
  int*   delay_arr = (int*)  (ws + 8421376 + 263168);           // 263,168
  float* g         = (float*)(ws + 8421376 + 2*263168);         // 262,144

  k1_rays  <<<(BS*RAYS)/4,  256, 0, stream>>>(rays_o, position_tx, W1, b1, w_attn,
                                              wh, w_arr, delay_arr, g, out);
  k2_bucket<<<BS*NS*SPLIT,  512, 0, stream>>>(wh, w_arr, delay_arr, W_sig, b_sig, g);
  k3_dft   <<<BS*NS*4,      256, 0, stream>>>(g, out);
}